// Round 1
// 226.869 us; speedup vs baseline: 1.0449x; 1.0449x over previous
//
#include <hip/hip_runtime.h>

#define N_NODES 8192
#define N_EDGES 262144
#define D 256
#define ADJ_WORDS 256     // 8192 bits per row / 32
#define MAX_DEG 128       // Poisson(33): P(deg>128) ~ 1e-40
#define AGG_BLOCKS 2048   // 4 waves/block, ONE row per wave -> 8192 waves
#define NPART 16          // BN partial-sum rows (atomicAdd fan-in: 2048/16 = 128 per addr)

typedef __attribute__((ext_vector_type(8))) short bf16x8;
typedef __attribute__((ext_vector_type(4))) float f32x4;

__device__ __forceinline__ short f2bf(float f) {
    unsigned u = __builtin_bit_cast(unsigned, f);
    u += 0x7fffu + ((u >> 16) & 1);   // round to nearest even
    return (short)(u >> 16);
}
__device__ __forceinline__ float bf2f(unsigned short u) {
    return __builtin_bit_cast(float, ((unsigned)u) << 16);
}

// ---- adjacency build (set-semantics bitmask + exact degree) + W->bf16 tail blocks ----
// grid covers E edges + N self-loops + 3*65536 weight elements exactly (1824 blocks).
__global__ __launch_bounds__(256) void build_adj(const int* __restrict__ ei,
                                                 unsigned* __restrict__ adj,
                                                 int* __restrict__ deg,
                                                 const float* __restrict__ W1,
                                                 const float* __restrict__ W2,
                                                 const float* __restrict__ W3,
                                                 unsigned short* __restrict__ Wb1,
                                                 unsigned short* __restrict__ Wb2,
                                                 unsigned short* __restrict__ Wb3) {
    int i = blockIdx.x * 256 + threadIdx.x;
    if (i >= N_EDGES + N_NODES) {      // weight-conversion tail
        int j = i - (N_EDGES + N_NODES);          // 0 .. 196607
        int which = j >> 16, k = j & 65535;
        const float* src = which == 0 ? W1 : which == 1 ? W2 : W3;
        unsigned short* dst = which == 0 ? Wb1 : which == 1 ? Wb2 : Wb3;
        dst[k] = (unsigned short)f2bf(src[k]);
        return;
    }
    int r, c;
    if (i < N_EDGES) {
        r = ei[i];
        c = ei[N_EDGES + i];
    } else {
        r = i - N_EDGES;               // self loop
        c = r;
    }
    unsigned bit = 1u << (c & 31);
    unsigned old = atomicOr(&adj[r * ADJ_WORDS + (c >> 5)], bit);
    if (!(old & bit)) atomicAdd(&deg[r], 1);   // count only newly-set bits (set semantics)
}

// ---------- bitmask -> neighbor list (idx + combined weight dinv_r*dinv_c) ----------
__device__ __forceinline__ void nbrs_body(const unsigned* __restrict__ adj,
                                          const int* __restrict__ deg,
                                          int* __restrict__ nbr_idx,
                                          float* __restrict__ nbr_w, int r) {
    const int t = threadIdx.x;
    const int lane = t & 63, wave = t >> 6;
    unsigned m = adj[r * ADJ_WORDS + t];
    int cnt = __popc(m);
    int x = cnt;
    #pragma unroll
    for (int off = 1; off < 64; off <<= 1) {
        int v = __shfl_up(x, off, 64);
        if (lane >= off) x += v;
    }
    __shared__ int wtot[4];
    if (lane == 63) wtot[wave] = x;
    __syncthreads();
    int woff = 0;
    #pragma unroll
    for (int w = 0; w < 4; w++) woff += (w < wave) ? wtot[w] : 0;
    int base = woff + x - cnt;       // exclusive prefix
    const float dr = rsqrtf((float)deg[r]);   // deg >= 1 (self loop)
    int* oi = nbr_idx + (size_t)r * MAX_DEG;
    float* ow = nbr_w + (size_t)r * MAX_DEG;
    while (m) {
        int b = __ffs(m) - 1;
        m &= m - 1;
        int c = (t << 5) + b;
        if (base < MAX_DEG) {
            oi[base] = c;
            ow[base] = dr * rsqrtf((float)deg[c]);
        }
        base++;
    }
}

// -------- Hb(bf16) = bnapply(Xsrc fp32) @ W^T + b  (MFMA 16x16x32 bf16) --------
// BN finalize folded in: APPLY blocks reduce NPART(16) atomic partial rows
// -> scale/shift in LDS. A = W (n rows), B = X (m cols): C/D col(lane&15)=m,
// row(q*4+reg)=n -> 8B packed bf16 stores.
template <bool APPLY, bool RELU>
__device__ __forceinline__ void gemm_body(const float* __restrict__ Xsrc,
                                          const float* __restrict__ psA,
                                          const float* __restrict__ psQ,
                                          const float* __restrict__ g,
                                          const float* __restrict__ be,
                                          const unsigned short* __restrict__ Wb,
                                          const float* __restrict__ bias,
                                          unsigned short* __restrict__ Hb,
                                          int bn, int bm) {
    __shared__ float ssc[256], ssh[256];
    const int tid = threadIdx.x;
    if (APPLY) {
        float s = 0.f, q = 0.f;
        #pragma unroll
        for (int i = 0; i < NPART; i++) {
            s += psA[i * 256 + tid];
            q += psQ[i * 256 + tid];
        }
        float mu = s * (1.0f / N_NODES);
        float var = q * (1.0f / N_NODES) - mu * mu;
        float rstd = rsqrtf(var + 1e-5f);
        float sc = g[tid] * rstd;
        ssc[tid] = sc;
        ssh[tid] = be[tid] - mu * sc;
        __syncthreads();
    }

    const int wave = tid >> 6, lane = tid & 63;
    const int l16 = lane & 15, q = lane >> 4;
    const int mrow0 = bm + wave * 32;

    f32x4 acc[2][4];
    #pragma unroll
    for (int i = 0; i < 2; i++)
        #pragma unroll
        for (int j = 0; j < 4; j++) acc[i][j] = (f32x4){0.f, 0.f, 0.f, 0.f};

    for (int k0 = 0; k0 < D; k0 += 32) {
        const int kq = k0 + q * 8;
        bf16x8 xb[2];
        float4 sc0, sc1, sh0, sh1;
        if (APPLY) {
            sc0 = *(const float4*)(ssc + kq);
            sc1 = *(const float4*)(ssc + kq + 4);
            sh0 = *(const float4*)(ssh + kq);
            sh1 = *(const float4*)(ssh + kq + 4);
        }
        #pragma unroll
        for (int mf = 0; mf < 2; mf++) {
            const float* xr = Xsrc + (size_t)(mrow0 + mf * 16 + l16) * D + kq;
            float4 a = *(const float4*)xr;
            float4 b = *(const float4*)(xr + 4);
            float v[8] = {a.x, a.y, a.z, a.w, b.x, b.y, b.z, b.w};
            if (APPLY) {
                float sc[8] = {sc0.x, sc0.y, sc0.z, sc0.w, sc1.x, sc1.y, sc1.z, sc1.w};
                float sh[8] = {sh0.x, sh0.y, sh0.z, sh0.w, sh1.x, sh1.y, sh1.z, sh1.w};
                #pragma unroll
                for (int j = 0; j < 8; j++) {
                    v[j] = fmaf(v[j], sc[j], sh[j]);
                    if (RELU) v[j] = fmaxf(v[j], 0.0f);
                }
            }
            #pragma unroll
            for (int j = 0; j < 8; j++) xb[mf][j] = f2bf(v[j]);
        }
        #pragma unroll
        for (int nf = 0; nf < 4; nf++) {
            bf16x8 wa = *(const bf16x8*)(Wb + (size_t)(bn + nf * 16 + l16) * D + kq);
            #pragma unroll
            for (int mf = 0; mf < 2; mf++)
                acc[mf][nf] = __builtin_amdgcn_mfma_f32_16x16x32_bf16(wa, xb[mf], acc[mf][nf], 0, 0, 0);
        }
    }

    #pragma unroll
    for (int mf = 0; mf < 2; mf++) {
        const int m = mrow0 + mf * 16 + l16;
        #pragma unroll
        for (int nf = 0; nf < 4; nf++) {
            const int nb = bn + nf * 16 + q * 4;
            float4 b4 = *(const float4*)(bias + nb);
            short4 o;
            o.x = f2bf(acc[mf][nf][0] + b4.x);
            o.y = f2bf(acc[mf][nf][1] + b4.y);
            o.z = f2bf(acc[mf][nf][2] + b4.z);
            o.w = f2bf(acc[mf][nf][3] + b4.w);
            *(short4*)(Hb + (size_t)m * D + nb) = o;
        }
    }
}

// ---- fused dispatch: layer-1 gemm (256 blocks, launched first) + build_nbrs (8192) ----
// Independent once Wb1 is ready (build_adj tail). gemm1 alone runs 1 block/CU; the
// 8192 light nbr blocks fill the idle SIMDs -> build phase hidden under gemm1.
__global__ __launch_bounds__(256) void gemm1_and_nbrs(const float* __restrict__ x,
                                                      const unsigned short* __restrict__ Wb1,
                                                      const float* __restrict__ b1,
                                                      unsigned short* __restrict__ Hb,
                                                      const unsigned* __restrict__ adj,
                                                      const int* __restrict__ deg,
                                                      int* __restrict__ nbr_idx,
                                                      float* __restrict__ nbr_w) {
    const int bg = blockIdx.x;
    if (bg < 256) {
        gemm_body<false, false>(x, nullptr, nullptr, nullptr, nullptr, Wb1, b1, Hb,
                                (bg & 3) * 64, (bg >> 2) * 128);
    } else {
        nbrs_body(adj, deg, nbr_idx, nbr_w, bg - 256);
    }
}

__global__ __launch_bounds__(256) void gemm_mfma_bn(const float* __restrict__ Xsrc,
                                                    const float* __restrict__ psA,
                                                    const float* __restrict__ psQ,
                                                    const float* __restrict__ g,
                                                    const float* __restrict__ be,
                                                    const unsigned short* __restrict__ Wb,
                                                    const float* __restrict__ bias,
                                                    unsigned short* __restrict__ Hb) {
    gemm_body<true, true>(Xsrc, psA, psQ, g, be, Wb, bias, Hb,
                          blockIdx.x * 64, blockIdx.y * 128);
}

// ------- G[r,:] = sum_j w * Hb[idx,:]  — ONE row per wave, 8-wide gather unroll.
// BN partials: block-level LDS reduce then atomicAdd into NPART(16) partial rows
// (replaces the 2-stage reduce_partials pass; 128 RMWs/address, hidden in drain). ----
__global__ __launch_bounds__(256) void aggregate_bf16(const int* __restrict__ nbr_idx,
                                                      const float* __restrict__ nbr_w,
                                                      const int* __restrict__ deg,
                                                      const unsigned short* __restrict__ Hb,
                                                      float* __restrict__ G,
                                                      float* __restrict__ psA,
                                                      float* __restrict__ psQ) {
    const int wave = threadIdx.x >> 6;
    const int lane = threadIdx.x & 63;
    const int ch = lane * 4;
    const int r = blockIdx.x * 4 + wave;

    int dg = deg[r]; if (dg > MAX_DEG) dg = MAX_DEG;
    const int* idx = nbr_idx + (size_t)r * MAX_DEG;
    const float* wt = nbr_w + (size_t)r * MAX_DEG;
    float4 A = make_float4(0.f, 0.f, 0.f, 0.f);
    int j = 0;
    for (; j + 8 <= dg; j += 8) {            // 8 independent gathers in flight
        int4 c0 = *(const int4*)(idx + j);
        int4 c1 = *(const int4*)(idx + j + 4);
        float4 w0 = *(const float4*)(wt + j);
        float4 w1 = *(const float4*)(wt + j + 4);
        ushort4 u0 = *(const ushort4*)(Hb + (size_t)c0.x * D + ch);
        ushort4 u1 = *(const ushort4*)(Hb + (size_t)c0.y * D + ch);
        ushort4 u2 = *(const ushort4*)(Hb + (size_t)c0.z * D + ch);
        ushort4 u3 = *(const ushort4*)(Hb + (size_t)c0.w * D + ch);
        ushort4 u4 = *(const ushort4*)(Hb + (size_t)c1.x * D + ch);
        ushort4 u5 = *(const ushort4*)(Hb + (size_t)c1.y * D + ch);
        ushort4 u6 = *(const ushort4*)(Hb + (size_t)c1.z * D + ch);
        ushort4 u7 = *(const ushort4*)(Hb + (size_t)c1.w * D + ch);
        A.x = fmaf(w0.x, bf2f(u0.x), A.x); A.y = fmaf(w0.x, bf2f(u0.y), A.y);
        A.z = fmaf(w0.x, bf2f(u0.z), A.z); A.w = fmaf(w0.x, bf2f(u0.w), A.w);
        A.x = fmaf(w0.y, bf2f(u1.x), A.x); A.y = fmaf(w0.y, bf2f(u1.y), A.y);
        A.z = fmaf(w0.y, bf2f(u1.z), A.z); A.w = fmaf(w0.y, bf2f(u1.w), A.w);
        A.x = fmaf(w0.z, bf2f(u2.x), A.x); A.y = fmaf(w0.z, bf2f(u2.y), A.y);
        A.z = fmaf(w0.z, bf2f(u2.z), A.z); A.w = fmaf(w0.z, bf2f(u2.w), A.w);
        A.x = fmaf(w0.w, bf2f(u3.x), A.x); A.y = fmaf(w0.w, bf2f(u3.y), A.y);
        A.z = fmaf(w0.w, bf2f(u3.z), A.z); A.w = fmaf(w0.w, bf2f(u3.w), A.w);
        A.x = fmaf(w1.x, bf2f(u4.x), A.x); A.y = fmaf(w1.x, bf2f(u4.y), A.y);
        A.z = fmaf(w1.x, bf2f(u4.z), A.z); A.w = fmaf(w1.x, bf2f(u4.w), A.w);
        A.x = fmaf(w1.y, bf2f(u5.x), A.x); A.y = fmaf(w1.y, bf2f(u5.y), A.y);
        A.z = fmaf(w1.y, bf2f(u5.z), A.z); A.w = fmaf(w1.y, bf2f(u5.w), A.w);
        A.x = fmaf(w1.z, bf2f(u6.x), A.x); A.y = fmaf(w1.z, bf2f(u6.y), A.y);
        A.z = fmaf(w1.z, bf2f(u6.z), A.z); A.w = fmaf(w1.z, bf2f(u6.w), A.w);
        A.x = fmaf(w1.w, bf2f(u7.x), A.x); A.y = fmaf(w1.w, bf2f(u7.y), A.y);
        A.z = fmaf(w1.w, bf2f(u7.z), A.z); A.w = fmaf(w1.w, bf2f(u7.w), A.w);
    }
    for (; j + 4 <= dg; j += 4) {
        int4 c0 = *(const int4*)(idx + j);
        float4 w0 = *(const float4*)(wt + j);
        ushort4 u0 = *(const ushort4*)(Hb + (size_t)c0.x * D + ch);
        ushort4 u1 = *(const ushort4*)(Hb + (size_t)c0.y * D + ch);
        ushort4 u2 = *(const ushort4*)(Hb + (size_t)c0.z * D + ch);
        ushort4 u3 = *(const ushort4*)(Hb + (size_t)c0.w * D + ch);
        A.x = fmaf(w0.x, bf2f(u0.x), A.x); A.y = fmaf(w0.x, bf2f(u0.y), A.y);
        A.z = fmaf(w0.x, bf2f(u0.z), A.z); A.w = fmaf(w0.x, bf2f(u0.w), A.w);
        A.x = fmaf(w0.y, bf2f(u1.x), A.x); A.y = fmaf(w0.y, bf2f(u1.y), A.y);
        A.z = fmaf(w0.y, bf2f(u1.z), A.z); A.w = fmaf(w0.y, bf2f(u1.w), A.w);
        A.x = fmaf(w0.z, bf2f(u2.x), A.x); A.y = fmaf(w0.z, bf2f(u2.y), A.y);
        A.z = fmaf(w0.z, bf2f(u2.z), A.z); A.w = fmaf(w0.z, bf2f(u2.w), A.w);
        A.x = fmaf(w0.w, bf2f(u3.x), A.x); A.y = fmaf(w0.w, bf2f(u3.y), A.y);
        A.z = fmaf(w0.w, bf2f(u3.z), A.z); A.w = fmaf(w0.w, bf2f(u3.w), A.w);
    }
    for (; j < dg; j++) {
        int c = idx[j];
        float w = wt[j];
        ushort4 u = *(const ushort4*)(Hb + (size_t)c * D + ch);
        A.x = fmaf(w, bf2f(u.x), A.x); A.y = fmaf(w, bf2f(u.y), A.y);
        A.z = fmaf(w, bf2f(u.z), A.z); A.w = fmaf(w, bf2f(u.w), A.w);
    }
    *(float4*)(G + (size_t)r * D + ch) = A;

    // ---- block-level BN partial sums -> atomic fan-in to NPART rows ----
    __shared__ float ls[4][256], lss[4][256];
    ls[wave][ch] = A.x; ls[wave][ch + 1] = A.y; ls[wave][ch + 2] = A.z; ls[wave][ch + 3] = A.w;
    lss[wave][ch] = A.x * A.x; lss[wave][ch + 1] = A.y * A.y;
    lss[wave][ch + 2] = A.z * A.z; lss[wave][ch + 3] = A.w * A.w;
    __syncthreads();
    const int t = threadIdx.x;
    const int prow = (blockIdx.x & (NPART - 1)) * 256;
    atomicAdd(&psA[prow + t], ls[0][t] + ls[1][t] + ls[2][t] + ls[3][t]);
    atomicAdd(&psQ[prow + t], lss[0][t] + lss[1][t] + lss[2][t] + lss[3][t]);
}

// ------- final BN apply -> fp32 d_out (no relu); finalize folded into prologue -------
__global__ __launch_bounds__(256) void bn_apply_out(const float* __restrict__ G,
                                                    const float* __restrict__ psA,
                                                    const float* __restrict__ psQ,
                                                    const float* __restrict__ g,
                                                    const float* __restrict__ be,
                                                    float* __restrict__ Out) {
    __shared__ float ssc[256], ssh[256];
    const int tid = threadIdx.x;
    {
        float s = 0.f, q = 0.f;
        #pragma unroll
        for (int i = 0; i < NPART; i++) {
            s += psA[i * 256 + tid];
            q += psQ[i * 256 + tid];
        }
        float mu = s * (1.0f / N_NODES);
        float var = q * (1.0f / N_NODES) - mu * mu;
        float rstd = rsqrtf(var + 1e-5f);
        float sc = g[tid] * rstd;
        ssc[tid] = sc;
        ssh[tid] = be[tid] - mu * sc;
        __syncthreads();
    }
    const int rows_per_block = 64;
    const int r0 = blockIdx.x * rows_per_block;
    const int ch = (tid & 63) * 4;
    const int rsub = tid >> 6;
    float4 sc = *(const float4*)(ssc + ch);
    float4 sh = *(const float4*)(ssh + ch);
    for (int rr = rsub; rr < rows_per_block; rr += 4) {
        const size_t off = (size_t)(r0 + rr) * D + ch;
        float4 v = *(const float4*)(G + off);
        v.x = fmaf(v.x, sc.x, sh.x);
        v.y = fmaf(v.y, sc.y, sh.y);
        v.z = fmaf(v.z, sc.z, sh.z);
        v.w = fmaf(v.w, sc.w, sh.w);
        *(float4*)(Out + off) = v;
    }
}

extern "C" void kernel_launch(void* const* d_in, const int* in_sizes, int n_in,
                              void* d_out, int out_size, void* d_ws, size_t ws_size,
                              hipStream_t stream) {
    const float* x  = (const float*)d_in[0];
    const int*   ei = (const int*)d_in[1];
    const float* W1 = (const float*)d_in[2];
    const float* b1 = (const float*)d_in[3];
    const float* W2 = (const float*)d_in[4];
    const float* b2 = (const float*)d_in[5];
    const float* W3 = (const float*)d_in[6];
    const float* b3 = (const float*)d_in[7];
    const float* g1 = (const float*)d_in[8];
    const float* be1 = (const float*)d_in[9];
    const float* g2 = (const float*)d_in[10];
    const float* be2 = (const float*)d_in[11];
    const float* g3 = (const float*)d_in[12];
    const float* be3 = (const float*)d_in[13];

    char* ws = (char*)d_ws;
    // zeroed region: [0, 8MB + 128KB) = adj(8MB) + deg(32KB) + 6 psum rows-arrays(96KB)
    unsigned*       adj  = (unsigned*)ws;                            // 8 MB (live through gemm1_and_nbrs!)
    int*            deg  = (int*)(ws + (8 << 20));                   // 32 KB
    float*          psA0 = (float*)(ws + (8 << 20) + (32 << 10));    // 16 KB each
    float*          psQ0 = psA0 + NPART * 256;
    float*          psA1 = psQ0 + NPART * 256;
    float*          psQ1 = psA1 + NPART * 256;
    float*          psA2 = psQ1 + NPART * 256;
    float*          psQ2 = psA2 + NPART * 256;
    unsigned short* Wb1  = (unsigned short*)(ws + (8 << 20) + (128 << 10));  // 128 KB each
    unsigned short* Wb2  = (unsigned short*)(ws + (8 << 20) + (256 << 10));
    unsigned short* Wb3  = (unsigned short*)(ws + (8 << 20) + (384 << 10));
    int*            nbr_idx = (int*)  (ws + (9 << 20));              // 4 MB
    float*          nbr_w   = (float*)(ws + (13 << 20));             // 4 MB
    float*          G       = (float*)(ws + (17 << 20));             // 8 MB
    unsigned short* Hb      = (unsigned short*)(ws + (25 << 20));    // 4 MB (no longer aliases adj)

    hipMemsetAsync(ws, 0, (8 << 20) + (128 << 10), stream);

    // edges + self-loops + 3*64K weight conversions = 466944 threads = 1824 blocks exactly
    build_adj<<<1824, 256, 0, stream>>>(ei, adj, deg, W1, W2, W3, Wb1, Wb2, Wb3);

    // ---- Layer 1 gemm co-scheduled with neighbor-list build (independent work)
    gemm1_and_nbrs<<<256 + N_NODES, 256, 0, stream>>>(x, Wb1, b1, Hb, adj, deg, nbr_idx, nbr_w);
    aggregate_bf16<<<AGG_BLOCKS, 256, 0, stream>>>(nbr_idx, nbr_w, deg, Hb, G, psA0, psQ0);

    dim3 ggrid(D / 64, N_NODES / 128);

    // ---- Layer 2 (BN1 finalize + apply + relu fused into gemm)
    gemm_mfma_bn<<<ggrid, 256, 0, stream>>>(G, psA0, psQ0, g1, be1, Wb2, b2, Hb);
    aggregate_bf16<<<AGG_BLOCKS, 256, 0, stream>>>(nbr_idx, nbr_w, deg, Hb, G, psA1, psQ1);

    // ---- Layer 3 (BN2 finalize + apply + relu fused into gemm)
    gemm_mfma_bn<<<ggrid, 256, 0, stream>>>(G, psA1, psQ1, g2, be2, Wb3, b3, Hb);
    aggregate_bf16<<<AGG_BLOCKS, 256, 0, stream>>>(nbr_idx, nbr_w, deg, Hb, G, psA2, psQ2);

    // ---- final BN3 finalize + apply -> d_out
    bn_apply_out<<<N_NODES / 64, 256, 0, stream>>>(G, psA2, psQ2, g3, be3, (float*)d_out);
}

// Round 2
// 215.741 us; speedup vs baseline: 1.0988x; 1.0516x over previous
//
#include <hip/hip_runtime.h>

#define N_NODES 8192
#define N_EDGES 262144
#define D 256
#define ADJ_WORDS 256     // 8192 bits per row / 32
#define MAX_DEG 128       // Poisson(33): P(deg>128) ~ 1e-40
#define AGG_BLOCKS 2048   // 4 waves/block, ONE row per wave -> 8192 waves
#define NPART 16          // BN partial-sum rows (atomicAdd fan-in: 2048/16 = 128 per addr)

typedef __attribute__((ext_vector_type(8))) short bf16x8;
typedef __attribute__((ext_vector_type(8))) unsigned short u16x8;
typedef __attribute__((ext_vector_type(4))) float f32x4;

__device__ __forceinline__ short f2bf(float f) {
    unsigned u = __builtin_bit_cast(unsigned, f);
    u += 0x7fffu + ((u >> 16) & 1);   // round to nearest even
    return (short)(u >> 16);
}
__device__ __forceinline__ float bf2f(unsigned short u) {
    return __builtin_bit_cast(float, ((unsigned)u) << 16);
}

// ---- adjacency build (set-semantics bitmask + exact degree) + W->bf16 tail blocks ----
__global__ __launch_bounds__(256) void build_adj(const int* __restrict__ ei,
                                                 unsigned* __restrict__ adj,
                                                 int* __restrict__ deg,
                                                 const float* __restrict__ W1,
                                                 const float* __restrict__ W2,
                                                 const float* __restrict__ W3,
                                                 unsigned short* __restrict__ Wb1,
                                                 unsigned short* __restrict__ Wb2,
                                                 unsigned short* __restrict__ Wb3) {
    int i = blockIdx.x * 256 + threadIdx.x;
    if (i >= N_EDGES + N_NODES) {      // weight-conversion tail
        int j = i - (N_EDGES + N_NODES);          // 0 .. 196607
        int which = j >> 16, k = j & 65535;
        const float* src = which == 0 ? W1 : which == 1 ? W2 : W3;
        unsigned short* dst = which == 0 ? Wb1 : which == 1 ? Wb2 : Wb3;
        dst[k] = (unsigned short)f2bf(src[k]);
        return;
    }
    int r, c;
    if (i < N_EDGES) {
        r = ei[i];
        c = ei[N_EDGES + i];
    } else {
        r = i - N_EDGES;               // self loop
        c = r;
    }
    unsigned bit = 1u << (c & 31);
    unsigned old = atomicOr(&adj[r * ADJ_WORDS + (c >> 5)], bit);
    if (!(old & bit)) atomicAdd(&deg[r], 1);   // count only newly-set bits (set semantics)
}

// ----- bitmask -> neighbor index list ONLY (weights are factored: dinv[c] is folded
// into the GEMM epilogue's Hb store, dinv[r] into the aggregate epilogue) -----
__device__ __forceinline__ void nbrs_body(const unsigned* __restrict__ adj,
                                          int* __restrict__ nbr_idx, int r) {
    const int t = threadIdx.x;
    const int lane = t & 63, wave = t >> 6;
    unsigned m = adj[r * ADJ_WORDS + t];
    int cnt = __popc(m);
    int x = cnt;
    #pragma unroll
    for (int off = 1; off < 64; off <<= 1) {
        int v = __shfl_up(x, off, 64);
        if (lane >= off) x += v;
    }
    __shared__ int wtot[4];
    if (lane == 63) wtot[wave] = x;
    __syncthreads();
    int woff = 0;
    #pragma unroll
    for (int w = 0; w < 4; w++) woff += (w < wave) ? wtot[w] : 0;
    int base = woff + x - cnt;       // exclusive prefix
    int* oi = nbr_idx + (size_t)r * MAX_DEG;
    while (m) {
        int b = __ffs(m) - 1;
        m &= m - 1;
        int c = (t << 5) + b;
        if (base < MAX_DEG) oi[base] = c;
        base++;
    }
}

// -------- Hb(bf16) = dinv[m] * (bnapply(Xsrc fp32) @ W^T + b)  (MFMA 16x16x32 bf16) ----
// BN finalize folded in: APPLY blocks reduce NPART(16) atomic partial rows.
// dinv[m] = rsqrt(deg[m]) folded into the epilogue store (weight factoring).
template <bool APPLY, bool RELU>
__device__ __forceinline__ void gemm_body(const float* __restrict__ Xsrc,
                                          const float* __restrict__ psA,
                                          const float* __restrict__ psQ,
                                          const float* __restrict__ g,
                                          const float* __restrict__ be,
                                          const unsigned short* __restrict__ Wb,
                                          const float* __restrict__ bias,
                                          const int* __restrict__ deg,
                                          unsigned short* __restrict__ Hb,
                                          int bn, int bm) {
    __shared__ float ssc[256], ssh[256];
    const int tid = threadIdx.x;
    if (APPLY) {
        float s = 0.f, q = 0.f;
        #pragma unroll
        for (int i = 0; i < NPART; i++) {
            s += psA[i * 256 + tid];
            q += psQ[i * 256 + tid];
        }
        float mu = s * (1.0f / N_NODES);
        float var = q * (1.0f / N_NODES) - mu * mu;
        float rstd = rsqrtf(var + 1e-5f);
        float sc = g[tid] * rstd;
        ssc[tid] = sc;
        ssh[tid] = be[tid] - mu * sc;
        __syncthreads();
    }

    const int wave = tid >> 6, lane = tid & 63;
    const int l16 = lane & 15, q = lane >> 4;
    const int mrow0 = bm + wave * 32;

    f32x4 acc[2][4];
    #pragma unroll
    for (int i = 0; i < 2; i++)
        #pragma unroll
        for (int j = 0; j < 4; j++) acc[i][j] = (f32x4){0.f, 0.f, 0.f, 0.f};

    for (int k0 = 0; k0 < D; k0 += 32) {
        const int kq = k0 + q * 8;
        bf16x8 xb[2];
        float4 sc0, sc1, sh0, sh1;
        if (APPLY) {
            sc0 = *(const float4*)(ssc + kq);
            sc1 = *(const float4*)(ssc + kq + 4);
            sh0 = *(const float4*)(ssh + kq);
            sh1 = *(const float4*)(ssh + kq + 4);
        }
        #pragma unroll
        for (int mf = 0; mf < 2; mf++) {
            const float* xr = Xsrc + (size_t)(mrow0 + mf * 16 + l16) * D + kq;
            float4 a = *(const float4*)xr;
            float4 b = *(const float4*)(xr + 4);
            float v[8] = {a.x, a.y, a.z, a.w, b.x, b.y, b.z, b.w};
            if (APPLY) {
                float sc[8] = {sc0.x, sc0.y, sc0.z, sc0.w, sc1.x, sc1.y, sc1.z, sc1.w};
                float sh[8] = {sh0.x, sh0.y, sh0.z, sh0.w, sh1.x, sh1.y, sh1.z, sh1.w};
                #pragma unroll
                for (int j = 0; j < 8; j++) {
                    v[j] = fmaf(v[j], sc[j], sh[j]);
                    if (RELU) v[j] = fmaxf(v[j], 0.0f);
                }
            }
            #pragma unroll
            for (int j = 0; j < 8; j++) xb[mf][j] = f2bf(v[j]);
        }
        #pragma unroll
        for (int nf = 0; nf < 4; nf++) {
            bf16x8 wa = *(const bf16x8*)(Wb + (size_t)(bn + nf * 16 + l16) * D + kq);
            #pragma unroll
            for (int mf = 0; mf < 2; mf++)
                acc[mf][nf] = __builtin_amdgcn_mfma_f32_16x16x32_bf16(wa, xb[mf], acc[mf][nf], 0, 0, 0);
        }
    }

    #pragma unroll
    for (int mf = 0; mf < 2; mf++) {
        const int m = mrow0 + mf * 16 + l16;
        const float di = rsqrtf((float)deg[m]);   // fold dinv[m] into stored row
        #pragma unroll
        for (int nf = 0; nf < 4; nf++) {
            const int nb = bn + nf * 16 + q * 4;
            float4 b4 = *(const float4*)(bias + nb);
            short4 o;
            o.x = f2bf((acc[mf][nf][0] + b4.x) * di);
            o.y = f2bf((acc[mf][nf][1] + b4.y) * di);
            o.z = f2bf((acc[mf][nf][2] + b4.z) * di);
            o.w = f2bf((acc[mf][nf][3] + b4.w) * di);
            *(short4*)(Hb + (size_t)m * D + nb) = o;
        }
    }
}

// ---- fused dispatch: layer-1 gemm (256 blocks, launched first) + build_nbrs (8192) ----
__global__ __launch_bounds__(256) void gemm1_and_nbrs(const float* __restrict__ x,
                                                      const unsigned short* __restrict__ Wb1,
                                                      const float* __restrict__ b1,
                                                      const int* __restrict__ deg,
                                                      unsigned short* __restrict__ Hb,
                                                      const unsigned* __restrict__ adj,
                                                      int* __restrict__ nbr_idx) {
    const int bg = blockIdx.x;
    if (bg < 256) {
        gemm_body<false, false>(x, nullptr, nullptr, nullptr, nullptr, Wb1, b1, deg, Hb,
                                (bg & 3) * 64, (bg >> 2) * 128);
    } else {
        nbrs_body(adj, nbr_idx, bg - 256);
    }
}

__global__ __launch_bounds__(256) void gemm_mfma_bn(const float* __restrict__ Xsrc,
                                                    const float* __restrict__ psA,
                                                    const float* __restrict__ psQ,
                                                    const float* __restrict__ g,
                                                    const float* __restrict__ be,
                                                    const unsigned short* __restrict__ Wb,
                                                    const float* __restrict__ bias,
                                                    const int* __restrict__ deg,
                                                    unsigned short* __restrict__ Hb) {
    gemm_body<true, true>(Xsrc, psA, psQ, g, be, Wb, bias, deg, Hb,
                          blockIdx.x * 64, blockIdx.y * 128);
}

// ------- G[r,:] = dinv[r] * sum_j Hb[idx_j,:]  (Hb rows pre-scaled by dinv[c]).
// ONE row per wave; lanes 0-31 take even neighbors, 32-63 odd; 8 ch x 16B per lane.
// 8 x ushort8 gathers in flight -> 2x bytes-in-flight vs ushort4, half the load instrs.
// BN partials: LDS block-reduce then atomicAdd into NPART(16) partial rows. -------
__global__ __launch_bounds__(256) void aggregate_bf16(const int* __restrict__ nbr_idx,
                                                      const int* __restrict__ deg,
                                                      const unsigned short* __restrict__ Hb,
                                                      float* __restrict__ G,
                                                      float* __restrict__ psA,
                                                      float* __restrict__ psQ) {
    const int wave = threadIdx.x >> 6;
    const int lane = threadIdx.x & 63;
    const int half = lane >> 5;          // neighbor-parity this lane handles
    const int l32 = lane & 31;
    const int ch = l32 * 8;              // 8 channels per lane
    const int r = blockIdx.x * 4 + wave;

    const int dgr = deg[r];
    int dg = dgr; if (dg > MAX_DEG) dg = MAX_DEG;
    const int* idx = nbr_idx + (size_t)r * MAX_DEG;
    const unsigned short* hb = Hb + ch;

    float A[8] = {0.f, 0.f, 0.f, 0.f, 0.f, 0.f, 0.f, 0.f};
    int base = 0;
    for (; base + 16 <= dg; base += 16) {         // 8 x 16B gathers in flight per lane
        const int* p = idx + base + half;
        int c0 = p[0], c1 = p[2], c2 = p[4], c3 = p[6];
        int c4 = p[8], c5 = p[10], c6 = p[12], c7 = p[14];
        u16x8 u0 = *(const u16x8*)(hb + (size_t)c0 * D);
        u16x8 u1 = *(const u16x8*)(hb + (size_t)c1 * D);
        u16x8 u2 = *(const u16x8*)(hb + (size_t)c2 * D);
        u16x8 u3 = *(const u16x8*)(hb + (size_t)c3 * D);
        u16x8 u4 = *(const u16x8*)(hb + (size_t)c4 * D);
        u16x8 u5 = *(const u16x8*)(hb + (size_t)c5 * D);
        u16x8 u6 = *(const u16x8*)(hb + (size_t)c6 * D);
        u16x8 u7 = *(const u16x8*)(hb + (size_t)c7 * D);
        #pragma unroll
        for (int i = 0; i < 8; i++) A[i] += bf2f(u0[i]);
        #pragma unroll
        for (int i = 0; i < 8; i++) A[i] += bf2f(u1[i]);
        #pragma unroll
        for (int i = 0; i < 8; i++) A[i] += bf2f(u2[i]);
        #pragma unroll
        for (int i = 0; i < 8; i++) A[i] += bf2f(u3[i]);
        #pragma unroll
        for (int i = 0; i < 8; i++) A[i] += bf2f(u4[i]);
        #pragma unroll
        for (int i = 0; i < 8; i++) A[i] += bf2f(u5[i]);
        #pragma unroll
        for (int i = 0; i < 8; i++) A[i] += bf2f(u6[i]);
        #pragma unroll
        for (int i = 0; i < 8; i++) A[i] += bf2f(u7[i]);
    }
    for (; base + 8 <= dg; base += 8) {           // 4-wide tier
        const int* p = idx + base + half;
        int c0 = p[0], c1 = p[2], c2 = p[4], c3 = p[6];
        u16x8 u0 = *(const u16x8*)(hb + (size_t)c0 * D);
        u16x8 u1 = *(const u16x8*)(hb + (size_t)c1 * D);
        u16x8 u2 = *(const u16x8*)(hb + (size_t)c2 * D);
        u16x8 u3 = *(const u16x8*)(hb + (size_t)c3 * D);
        #pragma unroll
        for (int i = 0; i < 8; i++) A[i] += bf2f(u0[i]);
        #pragma unroll
        for (int i = 0; i < 8; i++) A[i] += bf2f(u1[i]);
        #pragma unroll
        for (int i = 0; i < 8; i++) A[i] += bf2f(u2[i]);
        #pragma unroll
        for (int i = 0; i < 8; i++) A[i] += bf2f(u3[i]);
    }
    for (int j = base + half; j < dg; j += 2) {   // scalar tail (per-half trip count)
        int c = idx[j];
        u16x8 u = *(const u16x8*)(hb + (size_t)c * D);
        #pragma unroll
        for (int i = 0; i < 8; i++) A[i] += bf2f(u[i]);
    }

    // combine the two neighbor-parity halves (lane <-> lane^32), scale by dinv[r]
    const float dr = rsqrtf((float)dgr);
    #pragma unroll
    for (int i = 0; i < 8; i++) A[i] += __shfl_xor(A[i], 32, 64);
    const int cp = ch + half * 4;                 // this lane stores 4 of its 8 channels
    float4 o;
    o.x = A[half * 4 + 0] * dr;
    o.y = A[half * 4 + 1] * dr;
    o.z = A[half * 4 + 2] * dr;
    o.w = A[half * 4 + 3] * dr;
    *(float4*)(G + (size_t)r * D + cp) = o;

    // ---- block-level BN partial sums -> atomic fan-in to NPART rows ----
    __shared__ float ls[4][256], lss[4][256];
    ls[wave][cp] = o.x; ls[wave][cp + 1] = o.y; ls[wave][cp + 2] = o.z; ls[wave][cp + 3] = o.w;
    lss[wave][cp] = o.x * o.x; lss[wave][cp + 1] = o.y * o.y;
    lss[wave][cp + 2] = o.z * o.z; lss[wave][cp + 3] = o.w * o.w;
    __syncthreads();
    const int t = threadIdx.x;
    const int prow = (blockIdx.x & (NPART - 1)) * 256;
    atomicAdd(&psA[prow + t], ls[0][t] + ls[1][t] + ls[2][t] + ls[3][t]);
    atomicAdd(&psQ[prow + t], lss[0][t] + lss[1][t] + lss[2][t] + lss[3][t]);
}

// ------- final BN apply -> fp32 d_out (no relu); finalize folded into prologue -------
__global__ __launch_bounds__(256) void bn_apply_out(const float* __restrict__ G,
                                                    const float* __restrict__ psA,
                                                    const float* __restrict__ psQ,
                                                    const float* __restrict__ g,
                                                    const float* __restrict__ be,
                                                    float* __restrict__ Out) {
    __shared__ float ssc[256], ssh[256];
    const int tid = threadIdx.x;
    {
        float s = 0.f, q = 0.f;
        #pragma unroll
        for (int i = 0; i < NPART; i++) {
            s += psA[i * 256 + tid];
            q += psQ[i * 256 + tid];
        }
        float mu = s * (1.0f / N_NODES);
        float var = q * (1.0f / N_NODES) - mu * mu;
        float rstd = rsqrtf(var + 1e-5f);
        float sc = g[tid] * rstd;
        ssc[tid] = sc;
        ssh[tid] = be[tid] - mu * sc;
        __syncthreads();
    }
    const int rows_per_block = 64;
    const int r0 = blockIdx.x * rows_per_block;
    const int ch = (tid & 63) * 4;
    const int rsub = tid >> 6;
    float4 sc = *(const float4*)(ssc + ch);
    float4 sh = *(const float4*)(ssh + ch);
    for (int rr = rsub; rr < rows_per_block; rr += 4) {
        const size_t off = (size_t)(r0 + rr) * D + ch;
        float4 v = *(const float4*)(G + off);
        v.x = fmaf(v.x, sc.x, sh.x);
        v.y = fmaf(v.y, sc.y, sh.y);
        v.z = fmaf(v.z, sc.z, sh.z);
        v.w = fmaf(v.w, sc.w, sh.w);
        *(float4*)(Out + off) = v;
    }
}

extern "C" void kernel_launch(void* const* d_in, const int* in_sizes, int n_in,
                              void* d_out, int out_size, void* d_ws, size_t ws_size,
                              hipStream_t stream) {
    const float* x  = (const float*)d_in[0];
    const int*   ei = (const int*)d_in[1];
    const float* W1 = (const float*)d_in[2];
    const float* b1 = (const float*)d_in[3];
    const float* W2 = (const float*)d_in[4];
    const float* b2 = (const float*)d_in[5];
    const float* W3 = (const float*)d_in[6];
    const float* b3 = (const float*)d_in[7];
    const float* g1 = (const float*)d_in[8];
    const float* be1 = (const float*)d_in[9];
    const float* g2 = (const float*)d_in[10];
    const float* be2 = (const float*)d_in[11];
    const float* g3 = (const float*)d_in[12];
    const float* be3 = (const float*)d_in[13];

    char* ws = (char*)d_ws;
    // zeroed region: [0, 8MB + 128KB) = adj(8MB) + deg(32KB) + 6 psum arrays(96KB)
    unsigned*       adj  = (unsigned*)ws;                            // 8 MB (live through gemm1_and_nbrs)
    int*            deg  = (int*)(ws + (8 << 20));                   // 32 KB
    float*          psA0 = (float*)(ws + (8 << 20) + (32 << 10));    // 16 KB each
    float*          psQ0 = psA0 + NPART * 256;
    float*          psA1 = psQ0 + NPART * 256;
    float*          psQ1 = psA1 + NPART * 256;
    float*          psA2 = psQ1 + NPART * 256;
    float*          psQ2 = psA2 + NPART * 256;
    unsigned short* Wb1  = (unsigned short*)(ws + (8 << 20) + (128 << 10));  // 128 KB each
    unsigned short* Wb2  = (unsigned short*)(ws + (8 << 20) + (256 << 10));
    unsigned short* Wb3  = (unsigned short*)(ws + (8 << 20) + (384 << 10));
    int*            nbr_idx = (int*)  (ws + (9 << 20));              // 4 MB
    float*          G       = (float*)(ws + (13 << 20));             // 8 MB
    unsigned short* Hb      = (unsigned short*)(ws + (21 << 20));    // 4 MB

    hipMemsetAsync(ws, 0, (8 << 20) + (128 << 10), stream);

    // edges + self-loops + 3*64K weight conversions = 466944 threads = 1824 blocks exactly
    build_adj<<<1824, 256, 0, stream>>>(ei, adj, deg, W1, W2, W3, Wb1, Wb2, Wb3);

    // ---- Layer 1 gemm co-scheduled with neighbor-list build (independent work)
    gemm1_and_nbrs<<<256 + N_NODES, 256, 0, stream>>>(x, Wb1, b1, deg, Hb, adj, nbr_idx);
    aggregate_bf16<<<AGG_BLOCKS, 256, 0, stream>>>(nbr_idx, deg, Hb, G, psA0, psQ0);

    dim3 ggrid(D / 64, N_NODES / 128);

    // ---- Layer 2 (BN1 finalize + apply + relu fused into gemm)
    gemm_mfma_bn<<<ggrid, 256, 0, stream>>>(G, psA0, psQ0, g1, be1, Wb2, b2, deg, Hb);
    aggregate_bf16<<<AGG_BLOCKS, 256, 0, stream>>>(nbr_idx, deg, Hb, G, psA1, psQ1);

    // ---- Layer 3 (BN2 finalize + apply + relu fused into gemm)
    gemm_mfma_bn<<<ggrid, 256, 0, stream>>>(G, psA1, psQ1, g2, be2, Wb3, b3, deg, Hb);
    aggregate_bf16<<<AGG_BLOCKS, 256, 0, stream>>>(nbr_idx, deg, Hb, G, psA2, psQ2);

    // ---- final BN3 finalize + apply -> d_out
    bn_apply_out<<<N_NODES / 64, 256, 0, stream>>>(G, psA2, psQ2, g3, be3, (float*)d_out);
}